// Round 1
// baseline (1102.793 us; speedup 1.0000x reference)
//
#include <hip/hip_runtime.h>

// ---------------------------------------------------------------------------
// TTT base module: out = (scan(XC,XB,XA,coeff) ) @ Wo^T
//   XC = hs@Wq^T, XB = hs@Wk^T, XA = hs@Wv^T   (bf16 MFMA GEMMs)
//   coeff from sigmoid(hs@lw^T + lb)           (GEMM with N padded to 128)
//   scan: 128 blocks (B*NH) x 1 wave, W1 state in MFMA accumulators
// ---------------------------------------------------------------------------

typedef __attribute__((ext_vector_type(4))) float float4v;
typedef __attribute__((ext_vector_type(8))) __bf16 bf16x8;
typedef __attribute__((ext_vector_type(4))) short short4v;
typedef __attribute__((ext_vector_type(4))) unsigned int uint4v;

__device__ __forceinline__ unsigned short f2bf(float f) {
  unsigned int u = __builtin_bit_cast(unsigned int, f);
  u += 0x7FFFu + ((u >> 16) & 1u);
  return (unsigned short)(u >> 16);
}
__device__ __forceinline__ float bf2f(unsigned short s) {
  unsigned int u = ((unsigned int)s) << 16;
  return __builtin_bit_cast(float, u);
}
__device__ __forceinline__ void lds_load16(const void* g, void* l) {
  __builtin_amdgcn_global_load_lds((const __attribute__((address_space(1))) void*)g,
                                   (__attribute__((address_space(3))) void*)l, 16, 0, 0);
}

__device__ __forceinline__ void store_out(float* p, float v) { *p = v; }
__device__ __forceinline__ void store_out(unsigned short* p, float v) { *p = f2bf(v); }

// ---------------------------------------------------------------------------
// C[m,n] = sum_k A[m,k] * B[n,k]   (A: MxK bf16, B: NxK bf16 row-major)
// 128x128 tile, BK=32, 256 threads = 4 waves (2x2 of 64x64), 16x16x32 MFMA.
// M%128==0, N%128==0, K%32==0 assumed.
// ---------------------------------------------------------------------------
template <typename OUT>
__global__ __launch_bounds__(256) void gemm_bt(
    const unsigned short* __restrict__ A, const unsigned short* __restrict__ B,
    OUT* __restrict__ C, int M, int N, int K) {
  __shared__ unsigned short sA[128 * 32];
  __shared__ unsigned short sB[128 * 32];
  const int tid = threadIdx.x;
  const int wave = tid >> 6;
  const int lane = tid & 63;
  const int quad = lane >> 4;
  const int l15 = lane & 15;
  const int wm = (wave >> 1) * 64;
  const int wn = (wave & 1) * 64;
  const int bm = blockIdx.y * 128;
  const int bn = blockIdx.x * 128;

  float4v acc[4][4];
#pragma unroll
  for (int i = 0; i < 4; ++i)
#pragma unroll
    for (int j = 0; j < 4; ++j) acc[i][j] = (float4v){0.f, 0.f, 0.f, 0.f};

  // staging: thread t covers 16B at linear byte offset t*16 of the 128x32 tile
  const int srow = tid >> 2;         // 0..63
  const int scol = (tid & 3) * 8;    // 0,8,16,24
  const unsigned short* aptr = A + (size_t)(bm + srow) * K + scol;
  const unsigned short* bptr = B + (size_t)(bn + srow) * K + scol;
  unsigned short* sAw0 = &sA[wave * 512];
  unsigned short* sAw1 = &sA[2048 + wave * 512];
  unsigned short* sBw0 = &sB[wave * 512];
  unsigned short* sBw1 = &sB[2048 + wave * 512];
  const size_t astep = (size_t)64 * K;

  for (int kt = 0; kt < K; kt += 32) {
    __syncthreads();  // WAR: previous compute done before overwrite
    lds_load16(aptr + kt, sAw0);
    lds_load16(aptr + kt + astep, sAw1);
    lds_load16(bptr + kt, sBw0);
    lds_load16(bptr + kt + astep, sBw1);
    __syncthreads();  // drains vmcnt (global_load_lds) + barrier
    bf16x8 af[4], bf[4];
#pragma unroll
    for (int i = 0; i < 4; ++i)
      af[i] = *(const bf16x8*)&sA[(wm + i * 16 + l15) * 32 + quad * 8];
#pragma unroll
    for (int j = 0; j < 4; ++j)
      bf[j] = *(const bf16x8*)&sB[(wn + j * 16 + l15) * 32 + quad * 8];
#pragma unroll
    for (int i = 0; i < 4; ++i)
#pragma unroll
      for (int j = 0; j < 4; ++j)
        acc[i][j] = __builtin_amdgcn_mfma_f32_16x16x32_bf16(af[i], bf[j], acc[i][j], 0, 0, 0);
  }

#pragma unroll
  for (int i = 0; i < 4; ++i) {
    const int row0 = bm + wm + i * 16 + quad * 4;
#pragma unroll
    for (int j = 0; j < 4; ++j) {
      const int col = bn + wn + j * 16 + l15;
#pragma unroll
      for (int r = 0; r < 4; ++r)
        store_out(&C[(size_t)(row0 + r) * N + col], acc[i][j][r]);
    }
  }
}

// ---------------------------------------------------------------------------
// fp32 -> bf16 conversion (8 elems/thread)
// ---------------------------------------------------------------------------
__global__ __launch_bounds__(256) void f32_to_bf16_k(const float* __restrict__ s,
                                                     unsigned short* __restrict__ d, int n) {
  const int i = (blockIdx.x * 256 + threadIdx.x) * 8;
  if (i >= n) return;
  const float4v a = *(const float4v*)(s + i);
  const float4v b = *(const float4v*)(s + i + 4);
  uint4v o;
  o[0] = (unsigned int)f2bf(a[0]) | ((unsigned int)f2bf(a[1]) << 16);
  o[1] = (unsigned int)f2bf(a[2]) | ((unsigned int)f2bf(a[3]) << 16);
  o[2] = (unsigned int)f2bf(b[0]) | ((unsigned int)f2bf(b[1]) << 16);
  o[3] = (unsigned int)f2bf(b[2]) | ((unsigned int)f2bf(b[3]) << 16);
  *(uint4v*)(d + i) = o;
}

// ---------------------------------------------------------------------------
// coeff[b,h,c,k] = sigmoid(ilr[row,h] + lb[h]) / (64*(k+1))   (LR=1, HD=64)
// ---------------------------------------------------------------------------
__global__ __launch_bounds__(256) void coeff_k(const unsigned short* __restrict__ ilr,
                                               const float* __restrict__ lb,
                                               float* __restrict__ coeff) {
  const int gid = blockIdx.x * 256 + threadIdx.x;  // 8192*32
  const int row = gid >> 5;
  const int h = gid & 31;
  const float v = bf2f(ilr[row * 128 + h]) + lb[h];
  const float sig = 1.0f / (1.0f + __expf(-v));
  const int b = row >> 11;
  const int pos = row & 2047;
  const int cc = pos >> 4;
  const int k = pos & 15;
  coeff[((((size_t)b * 32 + h) * 128 + cc) << 4) + k] = sig / (64.0f * (float)(k + 1));
}

// ---------------------------------------------------------------------------
// TTT scan: one block = one (b,h); 1 wave; sequential over 128 chunks of K=16.
// W1 state: 16 fp32x4 MFMA accumulators (C-layout). b1 state in LDS.
// ---------------------------------------------------------------------------
__global__ __launch_bounds__(64, 1) void ttt_scan(
    const unsigned short* __restrict__ XC, const unsigned short* __restrict__ XB,
    const unsigned short* __restrict__ XA, const float* __restrict__ coeff,
    const float* __restrict__ lnw, const float* __restrict__ lnb,
    const float* __restrict__ W1i, const float* __restrict__ b1i,
    unsigned short* __restrict__ XCW) {
  const int b = blockIdx.x >> 5;
  const int h = blockIdx.x & 31;
  const int lane = threadIdx.x;
  const int quad = lane >> 4;
  const int l15 = lane & 15;

  __shared__ float sW1T[64 * 68];  // [g][f], stride 68 (b128-aligned)
  __shared__ float sXCs[16 * 68];  // [t][f]
  __shared__ float sXBs[16 * 68];
  __shared__ float sTs[16 * 68];   // xa - xb
  __shared__ float sAttn[16 * 20];
  __shared__ float sB1[64];
  __shared__ float sCo[16];

  float gam[4], bet[4];
#pragma unroll
  for (int nt = 0; nt < 4; ++nt) {
    gam[nt] = lnw[h * 64 + nt * 16 + l15];
    bet[nt] = lnb[h * 64 + nt * 16 + l15];
  }
  // W1 state, C-layout per 16x16 tile (mt,nt): elem (f=16mt+quad*4+r, g=16nt+l15)
  float4v W1r[16];
#pragma unroll
  for (int mt = 0; mt < 4; ++mt)
#pragma unroll
    for (int nt = 0; nt < 4; ++nt) {
      float4v v;
#pragma unroll
      for (int r = 0; r < 4; ++r)
        v[r] = W1i[(size_t)h * 4096 + (size_t)(mt * 16 + quad * 4 + r) * 64 + nt * 16 + l15];
      W1r[mt * 4 + nt] = v;
    }
  sB1[lane] = b1i[h * 64 + lane];

  const int srow = lane >> 2;        // 0..15
  const int scol = (lane & 3) * 16;  // 0,16,32,48
  const size_t hdoff = (size_t)h * 64;
  const size_t browoff = (size_t)b * 2048;
  const float inv64 = 1.0f / 64.0f;
  const float4v zero4 = {0.f, 0.f, 0.f, 0.f};

  for (int c = 0; c < 128; ++c) {
    __syncthreads();  // previous-iteration LDS reads done before restaging

    // ---- stage chunk: xc,xb,(xa-xb) rows + coeff + W1 snapshot ----
    const size_t goff = (browoff + (size_t)(c * 16 + srow)) * 2048 + hdoff + scol;
    uint4v xc0 = *(const uint4v*)(XC + goff);
    uint4v xc1 = *(const uint4v*)(XC + goff + 8);
    uint4v xb0 = *(const uint4v*)(XB + goff);
    uint4v xb1 = *(const uint4v*)(XB + goff + 8);
    uint4v xa0 = *(const uint4v*)(XA + goff);
    uint4v xa1 = *(const uint4v*)(XA + goff + 8);
    if (lane < 16) sCo[lane] = coeff[(((size_t)b * 32 + h) * 128 + c) * 16 + lane];

    float xcv[16], xbv[16], xav[16];
#pragma unroll
    for (int t2 = 0; t2 < 4; ++t2) {
      xcv[t2 * 2] = __builtin_bit_cast(float, xc0[t2] << 16);
      xcv[t2 * 2 + 1] = __builtin_bit_cast(float, xc0[t2] & 0xFFFF0000u);
      xcv[8 + t2 * 2] = __builtin_bit_cast(float, xc1[t2] << 16);
      xcv[8 + t2 * 2 + 1] = __builtin_bit_cast(float, xc1[t2] & 0xFFFF0000u);
      xbv[t2 * 2] = __builtin_bit_cast(float, xb0[t2] << 16);
      xbv[t2 * 2 + 1] = __builtin_bit_cast(float, xb0[t2] & 0xFFFF0000u);
      xbv[8 + t2 * 2] = __builtin_bit_cast(float, xb1[t2] << 16);
      xbv[8 + t2 * 2 + 1] = __builtin_bit_cast(float, xb1[t2] & 0xFFFF0000u);
      xav[t2 * 2] = __builtin_bit_cast(float, xa0[t2] << 16);
      xav[t2 * 2 + 1] = __builtin_bit_cast(float, xa0[t2] & 0xFFFF0000u);
      xav[8 + t2 * 2] = __builtin_bit_cast(float, xa1[t2] << 16);
      xav[8 + t2 * 2 + 1] = __builtin_bit_cast(float, xa1[t2] & 0xFFFF0000u);
    }
    const int sb = srow * 68 + scol;
#pragma unroll
    for (int e = 0; e < 16; ++e) {
      sXCs[sb + e] = xcv[e];
      sXBs[sb + e] = xbv[e];
      sTs[sb + e] = xav[e] - xbv[e];
    }
#pragma unroll
    for (int mt = 0; mt < 4; ++mt)
#pragma unroll
      for (int nt = 0; nt < 4; ++nt)
        *(float4v*)&sW1T[(nt * 16 + l15) * 68 + mt * 16 + quad * 4] = W1r[mt * 4 + nt];
    __syncthreads();

    // ---- fragments ----
    // A-frag (16x16x32): lane holds M[row=l15][k=hh*32+quad*8+j]
    bf16x8 xbf[2], xcf[2];
#pragma unroll
    for (int hh = 0; hh < 2; ++hh) {
      const float4v pb0 = *(const float4v*)&sXBs[l15 * 68 + hh * 32 + quad * 8];
      const float4v pb1 = *(const float4v*)&sXBs[l15 * 68 + hh * 32 + quad * 8 + 4];
      const float4v pc0 = *(const float4v*)&sXCs[l15 * 68 + hh * 32 + quad * 8];
      const float4v pc1 = *(const float4v*)&sXCs[l15 * 68 + hh * 32 + quad * 8 + 4];
      bf16x8 fb, fc;
#pragma unroll
      for (int r = 0; r < 4; ++r) {
        fb[r] = (__bf16)pb0[r]; fb[4 + r] = (__bf16)pb1[r];
        fc[r] = (__bf16)pc0[r]; fc[4 + r] = (__bf16)pc1[r];
      }
      xbf[hh] = fb; xcf[hh] = fc;
    }
    // B-frag of W1: lane holds W1[f=hh*32+quad*8+j][g=16nt+l15] = sW1T[g][f]
    bf16x8 w1f[4][2];
#pragma unroll
    for (int nt = 0; nt < 4; ++nt)
#pragma unroll
      for (int hh = 0; hh < 2; ++hh) {
        const float4v p0 = *(const float4v*)&sW1T[(nt * 16 + l15) * 68 + hh * 32 + quad * 8];
        const float4v p1 = *(const float4v*)&sW1T[(nt * 16 + l15) * 68 + hh * 32 + quad * 8 + 4];
        bf16x8 f;
#pragma unroll
        for (int r = 0; r < 4; ++r) { f[r] = (__bf16)p0[r]; f[4 + r] = (__bf16)p1[r]; }
        w1f[nt][hh] = f;
      }
    float cof[4];
#pragma unroll
    for (int r = 0; r < 4; ++r) cof[r] = sCo[quad * 4 + r];
    float b1v[4];
#pragma unroll
    for (int nt = 0; nt < 4; ++nt) b1v[nt] = sB1[nt * 16 + l15];

    // ---- Z1 = xb@W1 + b1  (C-layout: row t = quad*4+r, col g = 16nt+l15) ----
    float4v z[4];
#pragma unroll
    for (int nt = 0; nt < 4; ++nt) {
      float4v t = __builtin_amdgcn_mfma_f32_16x16x32_bf16(xbf[0], w1f[nt][0], zero4, 0, 0, 0);
      t = __builtin_amdgcn_mfma_f32_16x16x32_bf16(xbf[1], w1f[nt][1], t, 0, 0, 0);
#pragma unroll
      for (int r = 0; r < 4; ++r) t[r] += b1v[nt];
      z[nt] = t;
    }

    // ---- LN fused L2 backward -> grad (C-layout) ----
    float s1[4], s2[4];
#pragma unroll
    for (int r = 0; r < 4; ++r) {
      s1[r] = z[0][r] + z[1][r] + z[2][r] + z[3][r];
      s2[r] = z[0][r] * z[0][r] + z[1][r] * z[1][r] + z[2][r] * z[2][r] + z[3][r] * z[3][r];
    }
#pragma unroll
    for (int m = 1; m <= 8; m <<= 1)
#pragma unroll
      for (int r = 0; r < 4; ++r) {
        s1[r] += __shfl_xor(s1[r], m);
        s2[r] += __shfl_xor(s2[r], m);
      }
    float mu[4], rstd[4];
#pragma unroll
    for (int r = 0; r < 4; ++r) {
      mu[r] = s1[r] * inv64;
      const float var = s2[r] * inv64 - mu[r] * mu[r];
      rstd[r] = rsqrtf(var + 1e-6f);
    }
    float xh[4][4], gg[4][4];
#pragma unroll
    for (int nt = 0; nt < 4; ++nt)
#pragma unroll
      for (int r = 0; r < 4; ++r) {
        const float xhat = (z[nt][r] - mu[r]) * rstd[r];
        xh[nt][r] = xhat;
        const float y = gam[nt] * xhat + bet[nt];
        const float tgt = sTs[(quad * 4 + r) * 68 + nt * 16 + l15];
        gg[nt][r] = (y - tgt) * gam[nt];
      }
    float sg[4], sgx[4];
#pragma unroll
    for (int r = 0; r < 4; ++r) {
      sg[r] = gg[0][r] + gg[1][r] + gg[2][r] + gg[3][r];
      sgx[r] = gg[0][r] * xh[0][r] + gg[1][r] * xh[1][r] + gg[2][r] * xh[2][r] + gg[3][r] * xh[3][r];
    }
#pragma unroll
    for (int m = 1; m <= 8; m <<= 1)
#pragma unroll
      for (int r = 0; r < 4; ++r) {
        sg[r] += __shfl_xor(sg[r], m);
        sgx[r] += __shfl_xor(sgx[r], m);
      }
    float grad[4][4];
    short4v gradb[4];  // B-frag for 16x16x16: B[k=quad*4+jj][n=16nt+l15] == C-layout!
#pragma unroll
    for (int nt = 0; nt < 4; ++nt)
#pragma unroll
      for (int r = 0; r < 4; ++r) {
        grad[nt][r] = (64.0f * gg[nt][r] - sg[r] - xh[nt][r] * sgx[r]) * (rstd[r] * inv64);
        gradb[nt][r] = (short)f2bf(grad[nt][r]);
      }

    // ---- Attn = xc@xb^T (C-layout), transpose via LDS to A-frag ----
    float4v at = __builtin_amdgcn_mfma_f32_16x16x32_bf16(xcf[0], xbf[0], zero4, 0, 0, 0);
    at = __builtin_amdgcn_mfma_f32_16x16x32_bf16(xcf[1], xbf[1], at, 0, 0, 0);
#pragma unroll
    for (int r = 0; r < 4; ++r) sAttn[(quad * 4 + r) * 20 + l15] = at[r];
    __syncthreads();
    const float4v av = *(const float4v*)&sAttn[l15 * 20 + quad * 4];  // Attn[m=l15][k=quad*4+jj]
    // M1 = -((Attn+1) o E): folds (Attn*E)@grad + E@grad; A-frag for 16x16x16
    short4v m1f;
#pragma unroll
    for (int jj = 0; jj < 4; ++jj) {
      const int k = quad * 4 + jj;
      const float e = (k <= l15) ? cof[jj] : 0.0f;
      m1f[jj] = (short)f2bf(-(av[jj] + 1.0f) * e);
    }

    // ---- Z1_bar = xc@W1 - ((Attn+1) o E)@grad + b1 ----
#pragma unroll
    for (int nt = 0; nt < 4; ++nt) {
      float4v t = __builtin_amdgcn_mfma_f32_16x16x32_bf16(xcf[0], w1f[nt][0], zero4, 0, 0, 0);
      t = __builtin_amdgcn_mfma_f32_16x16x32_bf16(xcf[1], w1f[nt][1], t, 0, 0, 0);
      t = __builtin_amdgcn_mfma_f32_16x16x16bf16_1k(m1f, gradb[nt], t, 0, 0, 0);
#pragma unroll
      for (int r = 0; r < 4; ++r) t[r] += b1v[nt];
      z[nt] = t;
    }

    // ---- out = xc + LN(Z1_bar) ----
#pragma unroll
    for (int r = 0; r < 4; ++r) {
      s1[r] = z[0][r] + z[1][r] + z[2][r] + z[3][r];
      s2[r] = z[0][r] * z[0][r] + z[1][r] * z[1][r] + z[2][r] * z[2][r] + z[3][r] * z[3][r];
    }
#pragma unroll
    for (int m = 1; m <= 8; m <<= 1)
#pragma unroll
      for (int r = 0; r < 4; ++r) {
        s1[r] += __shfl_xor(s1[r], m);
        s2[r] += __shfl_xor(s2[r], m);
      }
#pragma unroll
    for (int r = 0; r < 4; ++r) {
      mu[r] = s1[r] * inv64;
      const float var = s2[r] * inv64 - mu[r] * mu[r];
      rstd[r] = rsqrtf(var + 1e-6f);
    }
#pragma unroll
    for (int nt = 0; nt < 4; ++nt)
#pragma unroll
      for (int r = 0; r < 4; ++r) {
        const float xhat = (z[nt][r] - mu[r]) * rstd[r];
        const float y = gam[nt] * xhat + bet[nt];
        const float o = sXCs[(quad * 4 + r) * 68 + nt * 16 + l15] + y;
        XCW[(browoff + (size_t)(c * 16 + quad * 4 + r)) * 2048 + hdoff + nt * 16 + l15] = f2bf(o);
      }

    // ---- b1 -= sum_t co_t * grad[t][:] ----
    float pb[4];
#pragma unroll
    for (int nt = 0; nt < 4; ++nt) {
      pb[nt] = cof[0] * grad[nt][0] + cof[1] * grad[nt][1] + cof[2] * grad[nt][2] + cof[3] * grad[nt][3];
      pb[nt] += __shfl_xor(pb[nt], 16);
      pb[nt] += __shfl_xor(pb[nt], 32);
    }
    if (lane < 16) {
#pragma unroll
      for (int nt = 0; nt < 4; ++nt) sB1[nt * 16 + lane] -= pb[nt];
    }

    // ---- W1 -= (co o xb)^T @ grad  (16 mfma accumulating into state) ----
#pragma unroll
    for (int mt = 0; mt < 4; ++mt) {
      short4v caf;  // A[m=16mt+l15][k=quad*4+jj] = -co_k * xb[k][16mt+l15]
#pragma unroll
      for (int jj = 0; jj < 4; ++jj)
        caf[jj] = (short)f2bf(-cof[jj] * sXBs[(quad * 4 + jj) * 68 + mt * 16 + l15]);
#pragma unroll
      for (int nt = 0; nt < 4; ++nt)
        W1r[mt * 4 + nt] =
            __builtin_amdgcn_mfma_f32_16x16x16bf16_1k(caf, gradb[nt], W1r[mt * 4 + nt], 0, 0, 0);
    }
  }
}

// ---------------------------------------------------------------------------
extern "C" void kernel_launch(void* const* d_in, const int* in_sizes, int n_in,
                              void* d_out, int out_size, void* d_ws, size_t ws_size,
                              hipStream_t stream) {
  const float* hs = (const float*)d_in[0];
  const float* Wq = (const float*)d_in[1];
  const float* Wk = (const float*)d_in[2];
  const float* Wv = (const float*)d_in[3];
  const float* Wo = (const float*)d_in[4];
  const float* lw = (const float*)d_in[5];
  const float* lb = (const float*)d_in[6];
  const float* lnw = (const float*)d_in[7];
  const float* lnb = (const float*)d_in[8];
  const float* W1i = (const float*)d_in[9];
  const float* b1i = (const float*)d_in[10];
  float* out = (float*)d_out;
  char* ws = (char*)d_ws;

  // workspace layout (bytes)
  unsigned short* hsb = (unsigned short*)(ws);               // 33554432 (hs bf16; reused as XCW)
  unsigned short* wqb = (unsigned short*)(ws + 33554432);    // 8388608
  unsigned short* wkb = (unsigned short*)(ws + 41943040);    // 8388608
  unsigned short* wvb = (unsigned short*)(ws + 50331648);    // 8388608
  unsigned short* wob = (unsigned short*)(ws + 58720256);    // 8388608
  unsigned short* lwb = (unsigned short*)(ws + 67108864);    // 524288 (128x2048, zero-padded)
  unsigned short* XCb = (unsigned short*)(ws + 67633152);    // 33554432
  unsigned short* XBb = (unsigned short*)(ws + 101187584);   // 33554432
  unsigned short* XAb = (unsigned short*)(ws + 134742016);   // 33554432
  unsigned short* ilrb = (unsigned short*)(ws + 168296448);  // 2097152
  float* coeff = (float*)(ws + 170393600);                   // 1048576 -> total 171442176

  f32_to_bf16_k<<<8192, 256, 0, stream>>>(hs, hsb, 16777216);
  f32_to_bf16_k<<<2048, 256, 0, stream>>>(Wq, wqb, 4194304);
  f32_to_bf16_k<<<2048, 256, 0, stream>>>(Wk, wkb, 4194304);
  f32_to_bf16_k<<<2048, 256, 0, stream>>>(Wv, wvb, 4194304);
  f32_to_bf16_k<<<2048, 256, 0, stream>>>(Wo, wob, 4194304);
  hipMemsetAsync(lwb, 0, 524288, stream);
  f32_to_bf16_k<<<32, 256, 0, stream>>>(lw, lwb, 65536);

  dim3 blk(256);
  dim3 gbig(16, 64);  // N/128, M/128
  gemm_bt<unsigned short><<<gbig, blk, 0, stream>>>(hsb, wqb, XCb, 8192, 2048, 2048);
  gemm_bt<unsigned short><<<gbig, blk, 0, stream>>>(hsb, wkb, XBb, 8192, 2048, 2048);
  gemm_bt<unsigned short><<<gbig, blk, 0, stream>>>(hsb, wvb, XAb, 8192, 2048, 2048);
  gemm_bt<unsigned short><<<dim3(1, 64), blk, 0, stream>>>(hsb, lwb, ilrb, 8192, 128, 2048);
  coeff_k<<<1024, 256, 0, stream>>>(ilrb, lb, coeff);
  ttt_scan<<<128, 64, 0, stream>>>(XCb, XBb, XAb, coeff, lnw, lnb, W1i, b1i, hsb);
  gemm_bt<float><<<gbig, blk, 0, stream>>>(hsb, wob, out, 8192, 2048, 2048);
}

// Round 2
// 1050.121 us; speedup vs baseline: 1.0502x; 1.0502x over previous
//
#include <hip/hip_runtime.h>

// ---------------------------------------------------------------------------
// TTT base module: out = (scan(XC,XB,XA,coeff) ) @ Wo^T
//   XC = hs@Wq^T, XB = hs@Wk^T, XA = hs@Wv^T   (bf16 MFMA GEMMs)
//   coeff from sigmoid(hs@lw^T + lb)           (GEMM with N padded to 128)
//   scan: 128 blocks (B*NH) x 1 wave, W1 state in MFMA accumulators.
//   Scan v2: no barriers (single wave => compiler lgkmcnt ordering suffices),
//   register-double-buffered chunk prefetch, shfl-broadcast coeff.
// ---------------------------------------------------------------------------

typedef __attribute__((ext_vector_type(4))) float float4v;
typedef __attribute__((ext_vector_type(8))) __bf16 bf16x8;
typedef __attribute__((ext_vector_type(4))) short short4v;
typedef __attribute__((ext_vector_type(4))) unsigned int uint4v;

__device__ __forceinline__ unsigned short f2bf(float f) {
  unsigned int u = __builtin_bit_cast(unsigned int, f);
  u += 0x7FFFu + ((u >> 16) & 1u);
  return (unsigned short)(u >> 16);
}
__device__ __forceinline__ float bf2f(unsigned short s) {
  unsigned int u = ((unsigned int)s) << 16;
  return __builtin_bit_cast(float, u);
}
__device__ __forceinline__ void lds_load16(const void* g, void* l) {
  __builtin_amdgcn_global_load_lds((const __attribute__((address_space(1))) void*)g,
                                   (__attribute__((address_space(3))) void*)l, 16, 0, 0);
}

__device__ __forceinline__ void store_out(float* p, float v) { *p = v; }
__device__ __forceinline__ void store_out(unsigned short* p, float v) { *p = f2bf(v); }

// ---------------------------------------------------------------------------
// C[m,n] = sum_k A[m,k] * B[n,k]   (A: MxK bf16, B: NxK bf16 row-major)
// 128x128 tile, BK=32, 256 threads = 4 waves (2x2 of 64x64), 16x16x32 MFMA.
// ---------------------------------------------------------------------------
template <typename OUT>
__global__ __launch_bounds__(256) void gemm_bt(
    const unsigned short* __restrict__ A, const unsigned short* __restrict__ B,
    OUT* __restrict__ C, int M, int N, int K) {
  __shared__ unsigned short sA[128 * 32];
  __shared__ unsigned short sB[128 * 32];
  const int tid = threadIdx.x;
  const int wave = tid >> 6;
  const int lane = tid & 63;
  const int quad = lane >> 4;
  const int l15 = lane & 15;
  const int wm = (wave >> 1) * 64;
  const int wn = (wave & 1) * 64;
  const int bm = blockIdx.y * 128;
  const int bn = blockIdx.x * 128;

  float4v acc[4][4];
#pragma unroll
  for (int i = 0; i < 4; ++i)
#pragma unroll
    for (int j = 0; j < 4; ++j) acc[i][j] = (float4v){0.f, 0.f, 0.f, 0.f};

  const int srow = tid >> 2;
  const int scol = (tid & 3) * 8;
  const unsigned short* aptr = A + (size_t)(bm + srow) * K + scol;
  const unsigned short* bptr = B + (size_t)(bn + srow) * K + scol;
  unsigned short* sAw0 = &sA[wave * 512];
  unsigned short* sAw1 = &sA[2048 + wave * 512];
  unsigned short* sBw0 = &sB[wave * 512];
  unsigned short* sBw1 = &sB[2048 + wave * 512];
  const size_t astep = (size_t)64 * K;

  for (int kt = 0; kt < K; kt += 32) {
    __syncthreads();
    lds_load16(aptr + kt, sAw0);
    lds_load16(aptr + kt + astep, sAw1);
    lds_load16(bptr + kt, sBw0);
    lds_load16(bptr + kt + astep, sBw1);
    __syncthreads();
    bf16x8 af[4], bf[4];
#pragma unroll
    for (int i = 0; i < 4; ++i)
      af[i] = *(const bf16x8*)&sA[(wm + i * 16 + l15) * 32 + quad * 8];
#pragma unroll
    for (int j = 0; j < 4; ++j)
      bf[j] = *(const bf16x8*)&sB[(wn + j * 16 + l15) * 32 + quad * 8];
#pragma unroll
    for (int i = 0; i < 4; ++i)
#pragma unroll
      for (int j = 0; j < 4; ++j)
        acc[i][j] = __builtin_amdgcn_mfma_f32_16x16x32_bf16(af[i], bf[j], acc[i][j], 0, 0, 0);
  }

#pragma unroll
  for (int i = 0; i < 4; ++i) {
    const int row0 = bm + wm + i * 16 + quad * 4;
#pragma unroll
    for (int j = 0; j < 4; ++j) {
      const int col = bn + wn + j * 16 + l15;
#pragma unroll
      for (int r = 0; r < 4; ++r)
        store_out(&C[(size_t)(row0 + r) * N + col], acc[i][j][r]);
    }
  }
}

// ---------------------------------------------------------------------------
__global__ __launch_bounds__(256) void f32_to_bf16_k(const float* __restrict__ s,
                                                     unsigned short* __restrict__ d, int n) {
  const int i = (blockIdx.x * 256 + threadIdx.x) * 8;
  if (i >= n) return;
  const float4v a = *(const float4v*)(s + i);
  const float4v b = *(const float4v*)(s + i + 4);
  uint4v o;
  o[0] = (unsigned int)f2bf(a[0]) | ((unsigned int)f2bf(a[1]) << 16);
  o[1] = (unsigned int)f2bf(a[2]) | ((unsigned int)f2bf(a[3]) << 16);
  o[2] = (unsigned int)f2bf(b[0]) | ((unsigned int)f2bf(b[1]) << 16);
  o[3] = (unsigned int)f2bf(b[2]) | ((unsigned int)f2bf(b[3]) << 16);
  *(uint4v*)(d + i) = o;
}

// ---------------------------------------------------------------------------
// coeff[b,h,c,k] = sigmoid(ilr[row,h] + lb[h]) / (64*(k+1))
// ---------------------------------------------------------------------------
__global__ __launch_bounds__(256) void coeff_k(const unsigned short* __restrict__ ilr,
                                               const float* __restrict__ lb,
                                               float* __restrict__ coeff) {
  const int gid = blockIdx.x * 256 + threadIdx.x;
  const int row = gid >> 5;
  const int h = gid & 31;
  const float v = bf2f(ilr[row * 128 + h]) + lb[h];
  const float sig = 1.0f / (1.0f + __expf(-v));
  const int b = row >> 11;
  const int pos = row & 2047;
  const int cc = pos >> 4;
  const int k = pos & 15;
  coeff[((((size_t)b * 32 + h) * 128 + cc) << 4) + k] = sig / (64.0f * (float)(k + 1));
}

// ---------------------------------------------------------------------------
// TTT scan v2: one block = one (b,h); 1 wave; 128 sequential chunks of K=16.
// No __syncthreads (single wave). Next-chunk globals prefetched into regs.
// ---------------------------------------------------------------------------
__global__ __launch_bounds__(64, 1) void ttt_scan(
    const unsigned short* __restrict__ XC, const unsigned short* __restrict__ XB,
    const unsigned short* __restrict__ XA, const float* __restrict__ coeff,
    const float* __restrict__ lnw, const float* __restrict__ lnb,
    const float* __restrict__ W1i, const float* __restrict__ b1i,
    unsigned short* __restrict__ XCW) {
  const int b = blockIdx.x >> 5;
  const int h = blockIdx.x & 31;
  const int lane = threadIdx.x;
  const int quad = lane >> 4;
  const int l15 = lane & 15;

  __shared__ float sW1T[64 * 68];  // [g][f], stride 68
  __shared__ float sXCs[16 * 68];  // [t][f]
  __shared__ float sXBs[16 * 68];
  __shared__ float sTs[16 * 68];   // xa - xb
  __shared__ float sAttn[16 * 20];
  __shared__ float sB1[64];

  float gam[4], bet[4];
#pragma unroll
  for (int nt = 0; nt < 4; ++nt) {
    gam[nt] = lnw[h * 64 + nt * 16 + l15];
    bet[nt] = lnb[h * 64 + nt * 16 + l15];
  }
  float4v W1r[16];
#pragma unroll
  for (int mt = 0; mt < 4; ++mt)
#pragma unroll
    for (int nt = 0; nt < 4; ++nt) {
      float4v v;
#pragma unroll
      for (int r = 0; r < 4; ++r)
        v[r] = W1i[(size_t)h * 4096 + (size_t)(mt * 16 + quad * 4 + r) * 64 + nt * 16 + l15];
      W1r[mt * 4 + nt] = v;
    }
  sB1[lane] = b1i[h * 64 + lane];

  const int srow = lane >> 2;
  const int scol = (lane & 3) * 16;
  const size_t hdoff = (size_t)h * 64;
  const size_t browoff = (size_t)b * 2048;
  const size_t cobase = (((size_t)b * 32 + h) * 128) * 16;
  const float inv64 = 1.0f / 64.0f;
  const float4v zero4 = {0.f, 0.f, 0.f, 0.f};

  // ---- prefetch chunk 0 ----
  uint4v pxc0, pxc1, pxb0, pxb1, pxa0, pxa1;
  float pco;
  {
    const size_t goff = (browoff + (size_t)srow) * 2048 + hdoff + scol;
    pxc0 = *(const uint4v*)(XC + goff);
    pxc1 = *(const uint4v*)(XC + goff + 8);
    pxb0 = *(const uint4v*)(XB + goff);
    pxb1 = *(const uint4v*)(XB + goff + 8);
    pxa0 = *(const uint4v*)(XA + goff);
    pxa1 = *(const uint4v*)(XA + goff + 8);
    pco = coeff[cobase + l15];
  }

  for (int c = 0; c < 128; ++c) {
    // consume prefetched chunk
    const uint4v xc0 = pxc0, xc1 = pxc1, xb0 = pxb0, xb1 = pxb1, xa0 = pxa0, xa1 = pxa1;
    const float co = pco;
    // issue prefetch for next chunk immediately (hidden under compute)
    {
      const int cn = (c < 127) ? c + 1 : 127;
      const size_t goff = (browoff + (size_t)(cn * 16 + srow)) * 2048 + hdoff + scol;
      pxc0 = *(const uint4v*)(XC + goff);
      pxc1 = *(const uint4v*)(XC + goff + 8);
      pxb0 = *(const uint4v*)(XB + goff);
      pxb1 = *(const uint4v*)(XB + goff + 8);
      pxa0 = *(const uint4v*)(XA + goff);
      pxa1 = *(const uint4v*)(XA + goff + 8);
      pco = coeff[cobase + (size_t)cn * 16 + l15];
    }

    float xcv[16], xbv[16], xav[16];
#pragma unroll
    for (int t2 = 0; t2 < 4; ++t2) {
      xcv[t2 * 2] = __builtin_bit_cast(float, xc0[t2] << 16);
      xcv[t2 * 2 + 1] = __builtin_bit_cast(float, xc0[t2] & 0xFFFF0000u);
      xcv[8 + t2 * 2] = __builtin_bit_cast(float, xc1[t2] << 16);
      xcv[8 + t2 * 2 + 1] = __builtin_bit_cast(float, xc1[t2] & 0xFFFF0000u);
      xbv[t2 * 2] = __builtin_bit_cast(float, xb0[t2] << 16);
      xbv[t2 * 2 + 1] = __builtin_bit_cast(float, xb0[t2] & 0xFFFF0000u);
      xbv[8 + t2 * 2] = __builtin_bit_cast(float, xb1[t2] << 16);
      xbv[8 + t2 * 2 + 1] = __builtin_bit_cast(float, xb1[t2] & 0xFFFF0000u);
      xav[t2 * 2] = __builtin_bit_cast(float, xa0[t2] << 16);
      xav[t2 * 2 + 1] = __builtin_bit_cast(float, xa0[t2] & 0xFFFF0000u);
      xav[8 + t2 * 2] = __builtin_bit_cast(float, xa1[t2] << 16);
      xav[8 + t2 * 2 + 1] = __builtin_bit_cast(float, xa1[t2] & 0xFFFF0000u);
    }
    const int sb = srow * 68 + scol;
#pragma unroll
    for (int e = 0; e < 16; ++e) {
      sXCs[sb + e] = xcv[e];
      sXBs[sb + e] = xbv[e];
      sTs[sb + e] = xav[e] - xbv[e];
    }
#pragma unroll
    for (int mt = 0; mt < 4; ++mt)
#pragma unroll
      for (int nt = 0; nt < 4; ++nt)
        *(float4v*)&sW1T[(nt * 16 + l15) * 68 + mt * 16 + quad * 4] = W1r[mt * 4 + nt];

    // ---- fragments (compiler inserts lgkmcnt waits; in-wave ordering ok) ----
    bf16x8 xbf[2], xcf[2];
#pragma unroll
    for (int hh = 0; hh < 2; ++hh) {
      const float4v pb0 = *(const float4v*)&sXBs[l15 * 68 + hh * 32 + quad * 8];
      const float4v pb1 = *(const float4v*)&sXBs[l15 * 68 + hh * 32 + quad * 8 + 4];
      const float4v pc0 = *(const float4v*)&sXCs[l15 * 68 + hh * 32 + quad * 8];
      const float4v pc1 = *(const float4v*)&sXCs[l15 * 68 + hh * 32 + quad * 8 + 4];
      bf16x8 fb, fc;
#pragma unroll
      for (int r = 0; r < 4; ++r) {
        fb[r] = (__bf16)pb0[r]; fb[4 + r] = (__bf16)pb1[r];
        fc[r] = (__bf16)pc0[r]; fc[4 + r] = (__bf16)pc1[r];
      }
      xbf[hh] = fb; xcf[hh] = fc;
    }
    bf16x8 w1f[4][2];
#pragma unroll
    for (int nt = 0; nt < 4; ++nt)
#pragma unroll
      for (int hh = 0; hh < 2; ++hh) {
        const float4v p0 = *(const float4v*)&sW1T[(nt * 16 + l15) * 68 + hh * 32 + quad * 8];
        const float4v p1 = *(const float4v*)&sW1T[(nt * 16 + l15) * 68 + hh * 32 + quad * 8 + 4];
        bf16x8 f;
#pragma unroll
        for (int r = 0; r < 4; ++r) { f[r] = (__bf16)p0[r]; f[4 + r] = (__bf16)p1[r]; }
        w1f[nt][hh] = f;
      }
    float cof[4];
#pragma unroll
    for (int r = 0; r < 4; ++r) cof[r] = __shfl(co, quad * 4 + r);
    float b1v[4];
#pragma unroll
    for (int nt = 0; nt < 4; ++nt) b1v[nt] = sB1[nt * 16 + l15];

    // ---- Z1 = xb@W1 + b1 ----
    float4v z[4];
#pragma unroll
    for (int nt = 0; nt < 4; ++nt) {
      float4v t = __builtin_amdgcn_mfma_f32_16x16x32_bf16(xbf[0], w1f[nt][0], zero4, 0, 0, 0);
      t = __builtin_amdgcn_mfma_f32_16x16x32_bf16(xbf[1], w1f[nt][1], t, 0, 0, 0);
#pragma unroll
      for (int r = 0; r < 4; ++r) t[r] += b1v[nt];
      z[nt] = t;
    }

    // ---- LN fused L2 backward -> grad ----
    float s1[4], s2[4];
#pragma unroll
    for (int r = 0; r < 4; ++r) {
      s1[r] = z[0][r] + z[1][r] + z[2][r] + z[3][r];
      s2[r] = z[0][r] * z[0][r] + z[1][r] * z[1][r] + z[2][r] * z[2][r] + z[3][r] * z[3][r];
    }
#pragma unroll
    for (int m = 1; m <= 8; m <<= 1)
#pragma unroll
      for (int r = 0; r < 4; ++r) {
        s1[r] += __shfl_xor(s1[r], m);
        s2[r] += __shfl_xor(s2[r], m);
      }
    float mu[4], rstd[4];
#pragma unroll
    for (int r = 0; r < 4; ++r) {
      mu[r] = s1[r] * inv64;
      const float var = s2[r] * inv64 - mu[r] * mu[r];
      rstd[r] = rsqrtf(var + 1e-6f);
    }
    float xh[4][4], gg[4][4];
#pragma unroll
    for (int nt = 0; nt < 4; ++nt)
#pragma unroll
      for (int r = 0; r < 4; ++r) {
        const float xhat = (z[nt][r] - mu[r]) * rstd[r];
        xh[nt][r] = xhat;
        const float y = gam[nt] * xhat + bet[nt];
        const float tgt = sTs[(quad * 4 + r) * 68 + nt * 16 + l15];
        gg[nt][r] = (y - tgt) * gam[nt];
      }
    float sg[4], sgx[4];
#pragma unroll
    for (int r = 0; r < 4; ++r) {
      sg[r] = gg[0][r] + gg[1][r] + gg[2][r] + gg[3][r];
      sgx[r] = gg[0][r] * xh[0][r] + gg[1][r] * xh[1][r] + gg[2][r] * xh[2][r] + gg[3][r] * xh[3][r];
    }
#pragma unroll
    for (int m = 1; m <= 8; m <<= 1)
#pragma unroll
      for (int r = 0; r < 4; ++r) {
        sg[r] += __shfl_xor(sg[r], m);
        sgx[r] += __shfl_xor(sgx[r], m);
      }
    float grad[4][4];
    short4v gradb[4];
#pragma unroll
    for (int nt = 0; nt < 4; ++nt)
#pragma unroll
      for (int r = 0; r < 4; ++r) {
        grad[nt][r] = (64.0f * gg[nt][r] - sg[r] - xh[nt][r] * sgx[r]) * (rstd[r] * inv64);
        gradb[nt][r] = (short)f2bf(grad[nt][r]);
      }

    // ---- Attn = xc@xb^T, transpose via LDS to A-frag ----
    float4v at = __builtin_amdgcn_mfma_f32_16x16x32_bf16(xcf[0], xbf[0], zero4, 0, 0, 0);
    at = __builtin_amdgcn_mfma_f32_16x16x32_bf16(xcf[1], xbf[1], at, 0, 0, 0);
#pragma unroll
    for (int r = 0; r < 4; ++r) sAttn[(quad * 4 + r) * 20 + l15] = at[r];
    const float4v av = *(const float4v*)&sAttn[l15 * 20 + quad * 4];
    short4v m1f;
#pragma unroll
    for (int jj = 0; jj < 4; ++jj) {
      const int k = quad * 4 + jj;
      const float e = (k <= l15) ? cof[jj] : 0.0f;
      m1f[jj] = (short)f2bf(-(av[jj] + 1.0f) * e);
    }

    // ---- Z1_bar = xc@W1 - ((Attn+1) o E)@grad + b1 ----
#pragma unroll
    for (int nt = 0; nt < 4; ++nt) {
      float4v t = __builtin_amdgcn_mfma_f32_16x16x32_bf16(xcf[0], w1f[nt][0], zero4, 0, 0, 0);
      t = __builtin_amdgcn_mfma_f32_16x16x32_bf16(xcf[1], w1f[nt][1], t, 0, 0, 0);
      t = __builtin_amdgcn_mfma_f32_16x16x16bf16_1k(m1f, gradb[nt], t, 0, 0, 0);
#pragma unroll
      for (int r = 0; r < 4; ++r) t[r] += b1v[nt];
      z[nt] = t;
    }

    // ---- out = xc + LN(Z1_bar) ----
#pragma unroll
    for (int r = 0; r < 4; ++r) {
      s1[r] = z[0][r] + z[1][r] + z[2][r] + z[3][r];
      s2[r] = z[0][r] * z[0][r] + z[1][r] * z[1][r] + z[2][r] * z[2][r] + z[3][r] * z[3][r];
    }
#pragma unroll
    for (int m = 1; m <= 8; m <<= 1)
#pragma unroll
      for (int r = 0; r < 4; ++r) {
        s1[r] += __shfl_xor(s1[r], m);
        s2[r] += __shfl_xor(s2[r], m);
      }
#pragma unroll
    for (int r = 0; r < 4; ++r) {
      mu[r] = s1[r] * inv64;
      const float var = s2[r] * inv64 - mu[r] * mu[r];
      rstd[r] = rsqrtf(var + 1e-6f);
    }
#pragma unroll
    for (int nt = 0; nt < 4; ++nt)
#pragma unroll
      for (int r = 0; r < 4; ++r) {
        const float xhat = (z[nt][r] - mu[r]) * rstd[r];
        const float y = gam[nt] * xhat + bet[nt];
        const float o = sXCs[(quad * 4 + r) * 68 + nt * 16 + l15] + y;
        XCW[(browoff + (size_t)(c * 16 + quad * 4 + r)) * 2048 + hdoff + nt * 16 + l15] = f2bf(o);
      }

    // ---- b1 -= sum_t co_t * grad[t][:] ----
    float pb[4];
#pragma unroll
    for (int nt = 0; nt < 4; ++nt) {
      pb[nt] = cof[0] * grad[nt][0] + cof[1] * grad[nt][1] + cof[2] * grad[nt][2] + cof[3] * grad[nt][3];
      pb[nt] += __shfl_xor(pb[nt], 16);
      pb[nt] += __shfl_xor(pb[nt], 32);
    }
    if (lane < 16) {
#pragma unroll
      for (int nt = 0; nt < 4; ++nt) sB1[nt * 16 + lane] -= pb[nt];
    }

    // ---- W1 -= (co o xb)^T @ grad ----
#pragma unroll
    for (int mt = 0; mt < 4; ++mt) {
      short4v caf;
#pragma unroll
      for (int jj = 0; jj < 4; ++jj)
        caf[jj] = (short)f2bf(-cof[jj] * sXBs[(quad * 4 + jj) * 68 + mt * 16 + l15]);
#pragma unroll
      for (int nt = 0; nt < 4; ++nt)
        W1r[mt * 4 + nt] =
            __builtin_amdgcn_mfma_f32_16x16x16bf16_1k(caf, gradb[nt], W1r[mt * 4 + nt], 0, 0, 0);
    }
  }
}

// ---------------------------------------------------------------------------
extern "C" void kernel_launch(void* const* d_in, const int* in_sizes, int n_in,
                              void* d_out, int out_size, void* d_ws, size_t ws_size,
                              hipStream_t stream) {
  const float* hs = (const float*)d_in[0];
  const float* Wq = (const float*)d_in[1];
  const float* Wk = (const float*)d_in[2];
  const float* Wv = (const float*)d_in[3];
  const float* Wo = (const float*)d_in[4];
  const float* lw = (const float*)d_in[5];
  const float* lb = (const float*)d_in[6];
  const float* lnw = (const float*)d_in[7];
  const float* lnb = (const float*)d_in[8];
  const float* W1i = (const float*)d_in[9];
  const float* b1i = (const float*)d_in[10];
  float* out = (float*)d_out;
  char* ws = (char*)d_ws;

  unsigned short* hsb = (unsigned short*)(ws);               // 33554432 (hs bf16; reused as XCW)
  unsigned short* wqb = (unsigned short*)(ws + 33554432);    // 8388608
  unsigned short* wkb = (unsigned short*)(ws + 41943040);    // 8388608
  unsigned short* wvb = (unsigned short*)(ws + 50331648);    // 8388608
  unsigned short* wob = (unsigned short*)(ws + 58720256);    // 8388608
  unsigned short* lwb = (unsigned short*)(ws + 67108864);    // 524288
  unsigned short* XCb = (unsigned short*)(ws + 67633152);    // 33554432
  unsigned short* XBb = (unsigned short*)(ws + 101187584);   // 33554432
  unsigned short* XAb = (unsigned short*)(ws + 134742016);   // 33554432
  unsigned short* ilrb = (unsigned short*)(ws + 168296448);  // 2097152
  float* coeff = (float*)(ws + 170393600);                   // 1048576

  f32_to_bf16_k<<<8192, 256, 0, stream>>>(hs, hsb, 16777216);
  f32_to_bf16_k<<<2048, 256, 0, stream>>>(Wq, wqb, 4194304);
  f32_to_bf16_k<<<2048, 256, 0, stream>>>(Wk, wkb, 4194304);
  f32_to_bf16_k<<<2048, 256, 0, stream>>>(Wv, wvb, 4194304);
  f32_to_bf16_k<<<2048, 256, 0, stream>>>(Wo, wob, 4194304);
  hipMemsetAsync(lwb, 0, 524288, stream);
  f32_to_bf16_k<<<32, 256, 0, stream>>>(lw, lwb, 65536);

  dim3 blk(256);
  dim3 gbig(16, 64);
  gemm_bt<unsigned short><<<gbig, blk, 0, stream>>>(hsb, wqb, XCb, 8192, 2048, 2048);
  gemm_bt<unsigned short><<<gbig, blk, 0, stream>>>(hsb, wkb, XBb, 8192, 2048, 2048);
  gemm_bt<unsigned short><<<gbig, blk, 0, stream>>>(hsb, wvb, XAb, 8192, 2048, 2048);
  gemm_bt<unsigned short><<<dim3(1, 64), blk, 0, stream>>>(hsb, lwb, ilrb, 8192, 128, 2048);
  coeff_k<<<1024, 256, 0, stream>>>(ilrb, lb, coeff);
  ttt_scan<<<128, 64, 0, stream>>>(XCb, XBb, XAb, coeff, lnw, lnb, W1i, b1i, hsb);
  gemm_bt<float><<<gbig, blk, 0, stream>>>(hsb, wob, out, 8192, 2048, 2048);
}